// Round 8
// baseline (1368.720 us; speedup 1.0000x reference)
//
#include <hip/hip_runtime.h>
#include <math.h>

#define N_NODES 50000
#define E_EDGES 800000
#define E_TOT   850000   // E + N self loops
#define HC 128
#define NHEAD 4
#define LIN 256
#define OUTC 10
#define NG 64
#define NEG_SLOPE 0.2f

__device__ __forceinline__ float lrelu(float v) { return v > 0.f ? v : NEG_SLOPE * v; }

// ---------------------------------------------------------------------------
// GEMM + attention logits: h = x@W (N x128 @ 128x128); alpha_{src,dst}[n,h].
// 4 rows x 16 cols per thread; cols interleaved (c = t*4 + 32u) so each
// ds_read_b128 hits all 32 banks conflict-free.
// ---------------------------------------------------------------------------
__global__ __launch_bounds__(256, 2) void k_gemm_alpha(
    const float* __restrict__ x, const float* __restrict__ W,
    const float* __restrict__ a_s, const float* __restrict__ a_d,
    float* __restrict__ h, float* __restrict__ asrc, float* __restrict__ adst) {
  __shared__ float Ws[HC * HC];  // 64 KB
  int tid = threadIdx.x;
  {
    const float4* Wg = (const float4*)W;
    float4* Wv = (float4*)Ws;
#pragma unroll
    for (int i = 0; i < 16; i++) Wv[tid + i * 256] = Wg[tid + i * 256];
  }
  __syncthreads();
  int rl = tid >> 3, t = tid & 7;
  int base = blockIdx.x * 128;
  int row[4];
  const float4* xr[4];
#pragma unroll
  for (int r = 0; r < 4; r++) {
    row[r] = base + rl + 32 * r;
    int rc = row[r] < N_NODES ? row[r] : N_NODES - 1;  // clamp, store-guarded
    xr[r] = (const float4*)(x + (size_t)rc * HC);
  }
  float acc[4][16];
#pragma unroll
  for (int r = 0; r < 4; r++)
#pragma unroll
    for (int j = 0; j < 16; j++) acc[r][j] = 0.f;

  for (int k4 = 0; k4 < 32; k4++) {
    float4 xa = xr[0][k4], xb = xr[1][k4], xc = xr[2][k4], xd = xr[3][k4];
#pragma unroll
    for (int kk = 0; kk < 4; kk++) {
      const float* wb = Ws + (k4 * 4 + kk) * HC + t * 4;
      float4 w0 = *(const float4*)(wb);
      float4 w1 = *(const float4*)(wb + 32);
      float4 w2 = *(const float4*)(wb + 64);
      float4 w3 = *(const float4*)(wb + 96);
      float xs[4];
      xs[0] = (kk == 0) ? xa.x : (kk == 1) ? xa.y : (kk == 2) ? xa.z : xa.w;
      xs[1] = (kk == 0) ? xb.x : (kk == 1) ? xb.y : (kk == 2) ? xb.z : xb.w;
      xs[2] = (kk == 0) ? xc.x : (kk == 1) ? xc.y : (kk == 2) ? xc.z : xc.w;
      xs[3] = (kk == 0) ? xd.x : (kk == 1) ? xd.y : (kk == 2) ? xd.z : xd.w;
#pragma unroll
      for (int r = 0; r < 4; r++) {
        float xv = xs[r];
        acc[r][0] += xv * w0.x;  acc[r][1] += xv * w0.y;
        acc[r][2] += xv * w0.z;  acc[r][3] += xv * w0.w;
        acc[r][4] += xv * w1.x;  acc[r][5] += xv * w1.y;
        acc[r][6] += xv * w1.z;  acc[r][7] += xv * w1.w;
        acc[r][8] += xv * w2.x;  acc[r][9] += xv * w2.y;
        acc[r][10] += xv * w2.z; acc[r][11] += xv * w2.w;
        acc[r][12] += xv * w3.x; acc[r][13] += xv * w3.y;
        acc[r][14] += xv * w3.z; acc[r][15] += xv * w3.w;
      }
    }
  }

#pragma unroll
  for (int r = 0; r < 4; r++) {
    // col c = t*4 + 32u + j  ->  head = u, channel = t*4 + j
    float ps[4], pd[4];
#pragma unroll
    for (int u = 0; u < 4; u++) {
      float s = 0.f, d = 0.f;
#pragma unroll
      for (int j = 0; j < 4; j++) {
        float av = acc[r][u * 4 + j];
        s += av * a_s[u * 32 + t * 4 + j];
        d += av * a_d[u * 32 + t * 4 + j];
      }
      s += __shfl_xor(s, 1); s += __shfl_xor(s, 2); s += __shfl_xor(s, 4);
      d += __shfl_xor(d, 1); d += __shfl_xor(d, 2); d += __shfl_xor(d, 4);
      ps[u] = s; pd[u] = d;
    }
    if (row[r] < N_NODES) {
      float* hr = h + (size_t)row[r] * HC;
#pragma unroll
      for (int u = 0; u < 4; u++)
        *(float4*)(hr + t * 4 + 32 * u) = make_float4(
            acc[r][u * 4 + 0], acc[r][u * 4 + 1], acc[r][u * 4 + 2], acc[r][u * 4 + 3]);
      if (t < 4) {
        float vs = (t == 0) ? ps[0] : (t == 1) ? ps[1] : (t == 2) ? ps[2] : ps[3];
        float vd = (t == 0) ? pd[0] : (t == 1) ? pd[1] : (t == 2) ? pd[2] : pd[3];
        asrc[row[r] * NHEAD + t] = vs;
        adst[row[r] * NHEAD + t] = vd;
      }
    }
  }
}

// ---------------------------------------------------------------------------
// CSR build: histogram -> exclusive scan -> scatter (int atomics only)
// ---------------------------------------------------------------------------
__global__ __launch_bounds__(256) void k_hist(
    const int* __restrict__ dst, int* __restrict__ deg) {
  int e = blockIdx.x * 256 + threadIdx.x;
  if (e >= E_TOT) return;
  int d = (e < E_EDGES) ? dst[e] : e - E_EDGES;
  atomicAdd(&deg[d], 1);
}

__global__ __launch_bounds__(1024) void k_scan(
    const int* __restrict__ deg, int* __restrict__ row_off,
    unsigned* __restrict__ pooled) {
  // fold the pooled zeroing in here (saves one dispatch)
  if (threadIdx.x < NG * HC / 8) {
    ((uint2*)pooled)[threadIdx.x * 4 + 0] = make_uint2(0u, 0u);
    ((uint2*)pooled)[threadIdx.x * 4 + 1] = make_uint2(0u, 0u);
    ((uint2*)pooled)[threadIdx.x * 4 + 2] = make_uint2(0u, 0u);
    ((uint2*)pooled)[threadIdx.x * 4 + 3] = make_uint2(0u, 0u);
  }
  __shared__ int ps[1024];
  int tid = threadIdx.x;
  const int CH = (N_NODES + 1023) / 1024;  // 49
  int base = tid * CH;
  int sum = 0;
  for (int i = 0; i < CH; i++) {
    int idx = base + i;
    if (idx < N_NODES) sum += deg[idx];
  }
  ps[tid] = sum;
  __syncthreads();
  for (int off = 1; off < 1024; off <<= 1) {
    int v = (tid >= off) ? ps[tid - off] : 0;
    __syncthreads();
    ps[tid] += v;
    __syncthreads();
  }
  int run = (tid ? ps[tid - 1] : 0);
  for (int i = 0; i < CH; i++) {
    int idx = base + i;
    if (idx < N_NODES) { row_off[idx] = run; run += deg[idx]; }
  }
  if (tid == 1023) row_off[N_NODES] = run;
}

__global__ __launch_bounds__(256) void k_scatter(
    const int* __restrict__ src, const int* __restrict__ dst,
    const int* __restrict__ row_off, int* __restrict__ cnt,
    int* __restrict__ csr_src) {
  int e = blockIdx.x * 256 + threadIdx.x;
  if (e >= E_TOT) return;
  int s, d;
  if (e < E_EDGES) { s = src[e]; d = dst[e]; } else { s = d = e - E_EDGES; }
  int pos = row_off[d] + atomicAdd(&cnt[d], 1);
  csr_src[pos] = s;
}

#define BFLY_MAX4(m0, m1, m2, m3)                         \
  _Pragma("unroll") for (int off = 1; off < 64; off <<= 1) { \
    m0 = fmaxf(m0, __shfl_xor(m0, off));                  \
    m1 = fmaxf(m1, __shfl_xor(m1, off));                  \
    m2 = fmaxf(m2, __shfl_xor(m2, off));                  \
    m3 = fmaxf(m3, __shfl_xor(m3, off));                  \
  }
#define BFLY_SUM4(s0, s1, s2, s3)                         \
  _Pragma("unroll") for (int off = 1; off < 64; off <<= 1) { \
    s0 += __shfl_xor(s0, off);                            \
    s1 += __shfl_xor(s1, off);                            \
    s2 += __shfl_xor(s2, off);                            \
    s3 += __shfl_xor(s3, off);                            \
  }

// ---------------------------------------------------------------------------
// Attention weights: one wave per dst node (proven R4/R6 stage-1 structure).
// Writes NORMALIZED per-edge weights into head-major planes:
//   wpl[head*E_TOT + j] = exp(e_j - m) / denom   for j in [lo,hi)
// ---------------------------------------------------------------------------
__global__ __launch_bounds__(256) void k_attn_w(
    const int* __restrict__ row_off, const int* __restrict__ csr_src,
    const float* __restrict__ asrc, const float* __restrict__ adst,
    float* __restrict__ wpl) {
  int gid = blockIdx.x * 256 + threadIdx.x;
  int node = gid >> 6, lane = gid & 63;
  if (node >= N_NODES) return;
  int lo = row_off[node], hi = row_off[node + 1];
  int deg = hi - lo;
  float4 ad4 = ((const float4*)adst)[node];  // broadcast

  if (deg <= 64) {
    int j = lo + lane;
    bool valid = (j < hi);
    int sv = valid ? csr_src[j] : 0;
    float4 a4 = ((const float4*)asrc)[sv];
    float e0 = valid ? lrelu(a4.x + ad4.x) : -1e30f;
    float e1 = valid ? lrelu(a4.y + ad4.y) : -1e30f;
    float e2 = valid ? lrelu(a4.z + ad4.z) : -1e30f;
    float e3 = valid ? lrelu(a4.w + ad4.w) : -1e30f;
    float m0 = e0, m1 = e1, m2 = e2, m3 = e3;
    BFLY_MAX4(m0, m1, m2, m3)
    float w0 = expf(e0 - m0), w1 = expf(e1 - m1);
    float w2 = expf(e2 - m2), w3 = expf(e3 - m3);  // invalid lanes -> 0
    float s0 = w0, s1 = w1, s2 = w2, s3 = w3;
    BFLY_SUM4(s0, s1, s2, s3)
    float r0 = 1.f / s0, r1 = 1.f / s1, r2 = 1.f / s2, r3 = 1.f / s3;
    if (valid) {
      wpl[0 * E_TOT + j] = w0 * r0;
      wpl[1 * E_TOT + j] = w1 * r1;
      wpl[2 * E_TOT + j] = w2 * r2;
      wpl[3 * E_TOT + j] = w3 * r3;
    }
    return;
  }

  // rare generic path (deg > 64): chunked three-pass
  float M0 = -1e30f, M1 = -1e30f, M2 = -1e30f, M3 = -1e30f;
  for (int c = lo; c < hi; c += 64) {
    int j = c + lane;
    bool valid = (j < hi);
    int sv = valid ? csr_src[j] : 0;
    float4 a4 = ((const float4*)asrc)[sv];
    float e0 = valid ? lrelu(a4.x + ad4.x) : -1e30f;
    float e1 = valid ? lrelu(a4.y + ad4.y) : -1e30f;
    float e2 = valid ? lrelu(a4.z + ad4.z) : -1e30f;
    float e3 = valid ? lrelu(a4.w + ad4.w) : -1e30f;
    BFLY_MAX4(e0, e1, e2, e3)
    M0 = fmaxf(M0, e0); M1 = fmaxf(M1, e1);
    M2 = fmaxf(M2, e2); M3 = fmaxf(M3, e3);
  }
  float S0 = 0.f, S1 = 0.f, S2 = 0.f, S3 = 0.f;
  for (int c = lo; c < hi; c += 64) {
    int j = c + lane;
    bool valid = (j < hi);
    int sv = valid ? csr_src[j] : 0;
    float4 a4 = ((const float4*)asrc)[sv];
    float w0 = valid ? expf(lrelu(a4.x + ad4.x) - M0) : 0.f;
    float w1 = valid ? expf(lrelu(a4.y + ad4.y) - M1) : 0.f;
    float w2 = valid ? expf(lrelu(a4.z + ad4.z) - M2) : 0.f;
    float w3 = valid ? expf(lrelu(a4.w + ad4.w) - M3) : 0.f;
    float s0 = w0, s1 = w1, s2 = w2, s3 = w3;
    BFLY_SUM4(s0, s1, s2, s3)
    S0 += s0; S1 += s1; S2 += s2; S3 += s3;
  }
  float r0 = 1.f / S0, r1 = 1.f / S1, r2 = 1.f / S2, r3 = 1.f / S3;
  for (int c = lo; c < hi; c += 64) {
    int j = c + lane;
    if (j < hi) {
      int sv = csr_src[j];
      float4 a4 = ((const float4*)asrc)[sv];
      wpl[0 * E_TOT + j] = expf(lrelu(a4.x + ad4.x) - M0) * r0;
      wpl[1 * E_TOT + j] = expf(lrelu(a4.y + ad4.y) - M1) * r1;
      wpl[2 * E_TOT + j] = expf(lrelu(a4.z + ad4.z) - M2) * r2;
      wpl[3 * E_TOT + j] = expf(lrelu(a4.w + ad4.w) - M3) * r3;
    }
  }
}

// ---------------------------------------------------------------------------
// XCD-sliced aggregation. slice s = blockIdx % 8 (dispatch round-robins
// blocks across XCDs %8, so slice ~= XCD). Slice s owns features
// [s*16, s*16+16) -> per-XCD h working set = 50000*64B = 3.2 MB < 4 MB L2.
// Block = 256 thr = 4 waves; wave = 4 node-groups of 16 lanes; lane owns 1
// feature. Per edge: one 64B line gather from (hot, local) L2. Weights are
// pre-normalized -> pure weighted sum. csr/weight streams use nontemporal
// loads so they don't evict the resident h slice. No LDS, low VGPR.
// ---------------------------------------------------------------------------
__global__ __launch_bounds__(256) void k_aggr_sliced(
    const int* __restrict__ row_off, const int* __restrict__ csr_src,
    const float* __restrict__ wpl, const float* __restrict__ h,
    const float* __restrict__ bias, const int* __restrict__ batch,
    float* __restrict__ out_h, unsigned* __restrict__ pooled, int do_pool) {
  int s  = blockIdx.x & 7;
  int nb = blockIdx.x >> 3;
  int wv = threadIdx.x >> 6;
  int lane = threadIdx.x & 63;
  int g = lane >> 4, fl = lane & 15;
  int node = nb * 16 + wv * 4 + g;
  if (node >= N_NODES) return;
  int f = s * 16 + fl;
  const float* wp = wpl + (size_t)(s >> 1) * E_TOT;  // head = f/32 = s/2
  int lo = row_off[node], hi = row_off[node + 1];

  float acc = 0.f;
  int j = lo;
  for (; j + 4 <= hi; j += 4) {
    int i0 = __builtin_nontemporal_load(csr_src + j + 0);
    int i1 = __builtin_nontemporal_load(csr_src + j + 1);
    int i2 = __builtin_nontemporal_load(csr_src + j + 2);
    int i3 = __builtin_nontemporal_load(csr_src + j + 3);
    float w0 = __builtin_nontemporal_load(wp + j + 0);
    float w1 = __builtin_nontemporal_load(wp + j + 1);
    float w2 = __builtin_nontemporal_load(wp + j + 2);
    float w3 = __builtin_nontemporal_load(wp + j + 3);
    float f0 = h[(size_t)i0 * HC + f];
    float f1 = h[(size_t)i1 * HC + f];
    float f2 = h[(size_t)i2 * HC + f];
    float f3 = h[(size_t)i3 * HC + f];
    acc = fmaf(w0, f0, acc);
    acc = fmaf(w1, f1, acc);
    acc = fmaf(w2, f2, acc);
    acc = fmaf(w3, f3, acc);
  }
  for (; j < hi; j++) {
    int i0 = __builtin_nontemporal_load(csr_src + j);
    float w0 = __builtin_nontemporal_load(wp + j);
    acc = fmaf(w0, h[(size_t)i0 * HC + f], acc);
  }

  float v = fmaxf(acc + bias[f], 0.f);
  __builtin_nontemporal_store(v, out_h + (size_t)node * HC + f);
  if (do_pool) {
    int gq = batch[node];
    // post-relu values >= 0: bit compare == float compare; init 0 matches
    // the reference's where(isfinite, pooled, 0) empty-graph guard.
    atomicMax(pooled + gq * HC + f, __float_as_uint(v));
  }
}

// final head: out[g] = (pooled[g] @ Wlin + blin) @ Wout + bout ; 1 block/graph
__global__ __launch_bounds__(256) void k_mlp(
    const float* __restrict__ pooled, const float* __restrict__ Wlin,
    const float* __restrict__ blin, const float* __restrict__ Wout,
    const float* __restrict__ bout, float* __restrict__ out) {
  __shared__ float p[HC];
  __shared__ float z[LIN];
  int g = blockIdx.x, tid = threadIdx.x;
  if (tid < HC) p[tid] = pooled[g * HC + tid];
  __syncthreads();
  float zv = blin[tid];
  for (int k = 0; k < HC; k++) zv += p[k] * Wlin[k * LIN + tid];
  z[tid] = zv;
  __syncthreads();
  if (tid < OUTC) {
    float o = bout[tid];
    for (int k = 0; k < LIN; k++) o += z[k] * Wout[k * OUTC + tid];
    out[g * OUTC + tid] = o;
  }
}

extern "C" void kernel_launch(void* const* d_in, const int* in_sizes, int n_in,
                              void* d_out, int out_size, void* d_ws, size_t ws_size,
                              hipStream_t stream) {
  const float* x     = (const float*)d_in[0];
  const int*   ei    = (const int*)d_in[1];
  const int*   batch = (const int*)d_in[2];
  const float* Wl[3] = {(const float*)d_in[3], (const float*)d_in[7], (const float*)d_in[11]};
  const float* As[3] = {(const float*)d_in[4], (const float*)d_in[8], (const float*)d_in[12]};
  const float* Ad[3] = {(const float*)d_in[5], (const float*)d_in[9], (const float*)d_in[13]};
  const float* Bi[3] = {(const float*)d_in[6], (const float*)d_in[10], (const float*)d_in[14]};
  const float* Wlin  = (const float*)d_in[15];
  const float* blin  = (const float*)d_in[16];
  const float* Wout  = (const float*)d_in[17];
  const float* bout  = (const float*)d_in[18];
  float* out = (float*)d_out;

  // workspace layout (float offsets), total ~17.61M floats = ~70.4 MB
  float* ws = (float*)d_ws;
  float*    h       = ws;                          // N*128
  float*    nodeB   = ws + 6400000;                // N*128
  float*    asrc    = ws + 12800000;               // N*4
  float*    adst    = ws + 13000000;               // N*4
  int*      deg     = (int*)(ws + 13200000);       // N
  int*      cnt     = (int*)(ws + 13250000);       // N (adjacent to deg)
  int*      row_off = (int*)(ws + 13300000);       // N+1
  int*      csr_src = (int*)(ws + 13350008);       // E_TOT
  float*    wpl     = ws + 14200008;               // 4*E_TOT (head-major planes)
  unsigned* pooled  = (unsigned*)(ws + 17600008);  // 64*128

  const int* srcp = ei;
  const int* dstp = ei + E_EDGES;

  hipMemsetAsync(deg, 0, 2 * N_NODES * sizeof(int), stream);

  // CSR by dst — built once, reused by all 3 layers
  k_hist<<<(E_TOT + 255) / 256, 256, 0, stream>>>(dstp, deg);
  k_scan<<<1, 1024, 0, stream>>>(deg, row_off, pooled);
  k_scatter<<<(E_TOT + 255) / 256, 256, 0, stream>>>(srcp, dstp, row_off, cnt, csr_src);

  const float* lin_in = x;
  for (int L = 0; L < 3; L++) {
    k_gemm_alpha<<<(N_NODES + 127) / 128, 256, 0, stream>>>(
        lin_in, Wl[L], As[L], Ad[L], h, asrc, adst);
    k_attn_w<<<(N_NODES * 64 + 255) / 256, 256, 0, stream>>>(
        row_off, csr_src, asrc, adst, wpl);
    k_aggr_sliced<<<((N_NODES + 15) / 16) * 8, 256, 0, stream>>>(
        row_off, csr_src, wpl, h, Bi[L], batch,
        nodeB, pooled, (L == 2) ? 1 : 0);
    lin_in = nodeB;
  }
  k_mlp<<<NG, 256, 0, stream>>>((const float*)pooled, Wlin, blin, Wout, bout, out);
}

// Round 9
// 593.037 us; speedup vs baseline: 2.3080x; 2.3080x over previous
//
#include <hip/hip_runtime.h>
#include <hip/hip_fp16.h>
#include <math.h>

#define N_NODES 50000
#define E_EDGES 800000
#define E_TOT   850000   // E + N self loops
#define HC 128
#define NHEAD 4
#define LIN 256
#define OUTC 10
#define NG 64
#define NEG_SLOPE 0.2f

__device__ __forceinline__ float lrelu(float v) { return v > 0.f ? v : NEG_SLOPE * v; }

// ---------------------------------------------------------------------------
// GEMM + attention logits: h = x@W (N x128 @ 128x128); alpha_{src,dst}[n,h].
// 4 rows x 16 cols per thread; cols interleaved (c = t*4 + 32u) so each
// ds_read_b128 hits all 32 banks conflict-free. h is emitted in FP16: its
// only consumer is the aggregation gather (halves gather bytes + lines).
// All arithmetic and alpha logits stay fp32.
// ---------------------------------------------------------------------------
__global__ __launch_bounds__(256, 2) void k_gemm_alpha(
    const float* __restrict__ x, const float* __restrict__ W,
    const float* __restrict__ a_s, const float* __restrict__ a_d,
    __half* __restrict__ h, float* __restrict__ asrc, float* __restrict__ adst) {
  __shared__ float Ws[HC * HC];  // 64 KB
  int tid = threadIdx.x;
  {
    const float4* Wg = (const float4*)W;
    float4* Wv = (float4*)Ws;
#pragma unroll
    for (int i = 0; i < 16; i++) Wv[tid + i * 256] = Wg[tid + i * 256];
  }
  __syncthreads();
  int rl = tid >> 3, t = tid & 7;
  int base = blockIdx.x * 128;
  int row[4];
  const float4* xr[4];
#pragma unroll
  for (int r = 0; r < 4; r++) {
    row[r] = base + rl + 32 * r;
    int rc = row[r] < N_NODES ? row[r] : N_NODES - 1;  // clamp, store-guarded
    xr[r] = (const float4*)(x + (size_t)rc * HC);
  }
  float acc[4][16];
#pragma unroll
  for (int r = 0; r < 4; r++)
#pragma unroll
    for (int j = 0; j < 16; j++) acc[r][j] = 0.f;

  for (int k4 = 0; k4 < 32; k4++) {
    float4 xa = xr[0][k4], xb = xr[1][k4], xc = xr[2][k4], xd = xr[3][k4];
#pragma unroll
    for (int kk = 0; kk < 4; kk++) {
      const float* wb = Ws + (k4 * 4 + kk) * HC + t * 4;
      float4 w0 = *(const float4*)(wb);
      float4 w1 = *(const float4*)(wb + 32);
      float4 w2 = *(const float4*)(wb + 64);
      float4 w3 = *(const float4*)(wb + 96);
      float xs[4];
      xs[0] = (kk == 0) ? xa.x : (kk == 1) ? xa.y : (kk == 2) ? xa.z : xa.w;
      xs[1] = (kk == 0) ? xb.x : (kk == 1) ? xb.y : (kk == 2) ? xb.z : xb.w;
      xs[2] = (kk == 0) ? xc.x : (kk == 1) ? xc.y : (kk == 2) ? xc.z : xc.w;
      xs[3] = (kk == 0) ? xd.x : (kk == 1) ? xd.y : (kk == 2) ? xd.z : xd.w;
#pragma unroll
      for (int r = 0; r < 4; r++) {
        float xv = xs[r];
        acc[r][0] += xv * w0.x;  acc[r][1] += xv * w0.y;
        acc[r][2] += xv * w0.z;  acc[r][3] += xv * w0.w;
        acc[r][4] += xv * w1.x;  acc[r][5] += xv * w1.y;
        acc[r][6] += xv * w1.z;  acc[r][7] += xv * w1.w;
        acc[r][8] += xv * w2.x;  acc[r][9] += xv * w2.y;
        acc[r][10] += xv * w2.z; acc[r][11] += xv * w2.w;
        acc[r][12] += xv * w3.x; acc[r][13] += xv * w3.y;
        acc[r][14] += xv * w3.z; acc[r][15] += xv * w3.w;
      }
    }
  }

#pragma unroll
  for (int r = 0; r < 4; r++) {
    // col c = t*4 + 32u + j  ->  head = u, channel = t*4 + j
    float ps[4], pd[4];
#pragma unroll
    for (int u = 0; u < 4; u++) {
      float s = 0.f, d = 0.f;
#pragma unroll
      for (int j = 0; j < 4; j++) {
        float av = acc[r][u * 4 + j];
        s += av * a_s[u * 32 + t * 4 + j];
        d += av * a_d[u * 32 + t * 4 + j];
      }
      s += __shfl_xor(s, 1); s += __shfl_xor(s, 2); s += __shfl_xor(s, 4);
      d += __shfl_xor(d, 1); d += __shfl_xor(d, 2); d += __shfl_xor(d, 4);
      ps[u] = s; pd[u] = d;
    }
    if (row[r] < N_NODES) {
      __half* hr = h + (size_t)row[r] * HC;
#pragma unroll
      for (int u = 0; u < 4; u++) {
        __half2* hp2 = (__half2*)(hr + t * 4 + 32 * u);
        hp2[0] = __floats2half2_rn(acc[r][u * 4 + 0], acc[r][u * 4 + 1]);
        hp2[1] = __floats2half2_rn(acc[r][u * 4 + 2], acc[r][u * 4 + 3]);
      }
      if (t < 4) {
        float vs = (t == 0) ? ps[0] : (t == 1) ? ps[1] : (t == 2) ? ps[2] : ps[3];
        float vd = (t == 0) ? pd[0] : (t == 1) ? pd[1] : (t == 2) ? pd[2] : pd[3];
        asrc[row[r] * NHEAD + t] = vs;
        adst[row[r] * NHEAD + t] = vd;
      }
    }
  }
}

// ---------------------------------------------------------------------------
// CSR build: histogram -> exclusive scan -> scatter (int atomics only)
// ---------------------------------------------------------------------------
__global__ __launch_bounds__(256) void k_hist(
    const int* __restrict__ dst, int* __restrict__ deg) {
  int e = blockIdx.x * 256 + threadIdx.x;
  if (e >= E_TOT) return;
  int d = (e < E_EDGES) ? dst[e] : e - E_EDGES;
  atomicAdd(&deg[d], 1);
}

__global__ __launch_bounds__(1024) void k_scan(
    const int* __restrict__ deg, int* __restrict__ row_off,
    unsigned* __restrict__ pooled) {
  // fold the pooled zeroing in here (saves one dispatch)
  if (threadIdx.x < NG * HC / 8) {
    ((uint2*)pooled)[threadIdx.x * 4 + 0] = make_uint2(0u, 0u);
    ((uint2*)pooled)[threadIdx.x * 4 + 1] = make_uint2(0u, 0u);
    ((uint2*)pooled)[threadIdx.x * 4 + 2] = make_uint2(0u, 0u);
    ((uint2*)pooled)[threadIdx.x * 4 + 3] = make_uint2(0u, 0u);
  }
  __shared__ int ps[1024];
  int tid = threadIdx.x;
  const int CH = (N_NODES + 1023) / 1024;  // 49
  int base = tid * CH;
  int sum = 0;
  for (int i = 0; i < CH; i++) {
    int idx = base + i;
    if (idx < N_NODES) sum += deg[idx];
  }
  ps[tid] = sum;
  __syncthreads();
  for (int off = 1; off < 1024; off <<= 1) {
    int v = (tid >= off) ? ps[tid - off] : 0;
    __syncthreads();
    ps[tid] += v;
    __syncthreads();
  }
  int run = (tid ? ps[tid - 1] : 0);
  for (int i = 0; i < CH; i++) {
    int idx = base + i;
    if (idx < N_NODES) { row_off[idx] = run; run += deg[idx]; }
  }
  if (tid == 1023) row_off[N_NODES] = run;
}

__global__ __launch_bounds__(256) void k_scatter(
    const int* __restrict__ src, const int* __restrict__ dst,
    const int* __restrict__ row_off, int* __restrict__ cnt,
    int* __restrict__ csr_src) {
  int e = blockIdx.x * 256 + threadIdx.x;
  if (e >= E_TOT) return;
  int s, d;
  if (e < E_EDGES) { s = src[e]; d = dst[e]; } else { s = d = e - E_EDGES; }
  int pos = row_off[d] + atomicAdd(&cnt[d], 1);
  csr_src[pos] = s;
}

#define BFLY_MAX4(m0, m1, m2, m3)                         \
  _Pragma("unroll") for (int off = 1; off < 64; off <<= 1) { \
    m0 = fmaxf(m0, __shfl_xor(m0, off));                  \
    m1 = fmaxf(m1, __shfl_xor(m1, off));                  \
    m2 = fmaxf(m2, __shfl_xor(m2, off));                  \
    m3 = fmaxf(m3, __shfl_xor(m3, off));                  \
  }
#define BFLY_SUM4(s0, s1, s2, s3)                         \
  _Pragma("unroll") for (int off = 1; off < 64; off <<= 1) { \
    s0 += __shfl_xor(s0, off);                            \
    s1 += __shfl_xor(s1, off);                            \
    s2 += __shfl_xor(s2, off);                            \
    s3 += __shfl_xor(s3, off);                            \
  }

// ---------------------------------------------------------------------------
// Fused softmax + aggregation — EXACT R6 structure (known good, 158 us),
// with h gathered as fp16 (__half2 per lane: half the bytes & lines/edge).
// One wave per dst node; lane owns 2 feats; head = lane/16.
// ---------------------------------------------------------------------------
__global__ __launch_bounds__(256) void k_aggr(
    const int* __restrict__ row_off, const int* __restrict__ csr_src,
    const float* __restrict__ asrc, const float* __restrict__ adst,
    const __half* __restrict__ h, const float* __restrict__ bias,
    const int* __restrict__ batch, float* __restrict__ out_h,
    unsigned* __restrict__ pooled, int do_pool) {
  __shared__ int   sv_lds[4][64];
  __shared__ float w_lds[4][64][4];
  int gid = blockIdx.x * 256 + threadIdx.x;
  int node = gid >> 6, lane = gid & 63, wl = threadIdx.x >> 6;
  if (node >= N_NODES) return;
  int head = lane >> 4;
  int lo = row_off[node], hi = row_off[node + 1];
  int deg = hi - lo;
  float4 ad4 = ((const float4*)adst)[node];  // broadcast
  float ax = 0.f, ay = 0.f;
  float S;

  if (deg <= 64) {
    int j = lo + lane;
    int sv = (j < hi) ? csr_src[j] : 0;
    float4 a4 = ((const float4*)asrc)[sv];
    bool valid = (j < hi);
    float e0 = valid ? lrelu(a4.x + ad4.x) : -1e30f;
    float e1 = valid ? lrelu(a4.y + ad4.y) : -1e30f;
    float e2 = valid ? lrelu(a4.z + ad4.z) : -1e30f;
    float e3 = valid ? lrelu(a4.w + ad4.w) : -1e30f;
    float m0 = e0, m1 = e1, m2 = e2, m3 = e3;
    BFLY_MAX4(m0, m1, m2, m3)
    float w0 = expf(e0 - m0), w1 = expf(e1 - m1);
    float w2 = expf(e2 - m2), w3 = expf(e3 - m3);  // invalid lanes -> 0
    float s0 = w0, s1 = w1, s2 = w2, s3 = w3;
    BFLY_SUM4(s0, s1, s2, s3)
    sv_lds[wl][lane] = sv;
    *(float4*)&w_lds[wl][lane][0] = make_float4(w0, w1, w2, w3);
    S = (head == 0) ? s0 : (head == 1) ? s1 : (head == 2) ? s2 : s3;
    int jj = 0;
    for (; jj + 8 <= deg; jj += 8) {
      int i0 = sv_lds[wl][jj + 0], i1 = sv_lds[wl][jj + 1];
      int i2 = sv_lds[wl][jj + 2], i3 = sv_lds[wl][jj + 3];
      int i4 = sv_lds[wl][jj + 4], i5 = sv_lds[wl][jj + 5];
      int i6 = sv_lds[wl][jj + 6], i7 = sv_lds[wl][jj + 7];
      float wA = w_lds[wl][jj + 0][head], wB = w_lds[wl][jj + 1][head];
      float wC = w_lds[wl][jj + 2][head], wD = w_lds[wl][jj + 3][head];
      float wE = w_lds[wl][jj + 4][head], wF = w_lds[wl][jj + 5][head];
      float wG = w_lds[wl][jj + 6][head], wH = w_lds[wl][jj + 7][head];
      float2 h0 = __half22float2(*(const __half2*)(h + (size_t)i0 * HC + lane * 2));
      float2 h1 = __half22float2(*(const __half2*)(h + (size_t)i1 * HC + lane * 2));
      float2 h2 = __half22float2(*(const __half2*)(h + (size_t)i2 * HC + lane * 2));
      float2 h3 = __half22float2(*(const __half2*)(h + (size_t)i3 * HC + lane * 2));
      float2 h4 = __half22float2(*(const __half2*)(h + (size_t)i4 * HC + lane * 2));
      float2 h5 = __half22float2(*(const __half2*)(h + (size_t)i5 * HC + lane * 2));
      float2 h6 = __half22float2(*(const __half2*)(h + (size_t)i6 * HC + lane * 2));
      float2 h7 = __half22float2(*(const __half2*)(h + (size_t)i7 * HC + lane * 2));
      ax += wA * h0.x; ay += wA * h0.y;
      ax += wB * h1.x; ay += wB * h1.y;
      ax += wC * h2.x; ay += wC * h2.y;
      ax += wD * h3.x; ay += wD * h3.y;
      ax += wE * h4.x; ay += wE * h4.y;
      ax += wF * h5.x; ay += wF * h5.y;
      ax += wG * h6.x; ay += wG * h6.y;
      ax += wH * h7.x; ay += wH * h7.y;
    }
    for (; jj + 4 <= deg; jj += 4) {
      int i0 = sv_lds[wl][jj + 0], i1 = sv_lds[wl][jj + 1];
      int i2 = sv_lds[wl][jj + 2], i3 = sv_lds[wl][jj + 3];
      float wA = w_lds[wl][jj + 0][head], wB = w_lds[wl][jj + 1][head];
      float wC = w_lds[wl][jj + 2][head], wD = w_lds[wl][jj + 3][head];
      float2 h0 = __half22float2(*(const __half2*)(h + (size_t)i0 * HC + lane * 2));
      float2 h1 = __half22float2(*(const __half2*)(h + (size_t)i1 * HC + lane * 2));
      float2 h2 = __half22float2(*(const __half2*)(h + (size_t)i2 * HC + lane * 2));
      float2 h3 = __half22float2(*(const __half2*)(h + (size_t)i3 * HC + lane * 2));
      ax += wA * h0.x; ay += wA * h0.y;
      ax += wB * h1.x; ay += wB * h1.y;
      ax += wC * h2.x; ay += wC * h2.y;
      ax += wD * h3.x; ay += wD * h3.y;
    }
    for (; jj < deg; jj++) {
      int i0 = sv_lds[wl][jj];
      float wA = w_lds[wl][jj][head];
      float2 h0 = __half22float2(*(const __half2*)(h + (size_t)i0 * HC + lane * 2));
      ax += wA * h0.x; ay += wA * h0.y;
    }
  } else {
    // rare generic path (deg > 64): chunked two-pass
    float M0 = -1e30f, M1 = -1e30f, M2 = -1e30f, M3 = -1e30f;
    for (int c = lo; c < hi; c += 64) {
      int j = c + lane;
      int sv = (j < hi) ? csr_src[j] : 0;
      float4 a4 = ((const float4*)asrc)[sv];
      bool valid = (j < hi);
      float e0 = valid ? lrelu(a4.x + ad4.x) : -1e30f;
      float e1 = valid ? lrelu(a4.y + ad4.y) : -1e30f;
      float e2 = valid ? lrelu(a4.z + ad4.z) : -1e30f;
      float e3 = valid ? lrelu(a4.w + ad4.w) : -1e30f;
      BFLY_MAX4(e0, e1, e2, e3)
      M0 = fmaxf(M0, e0); M1 = fmaxf(M1, e1);
      M2 = fmaxf(M2, e2); M3 = fmaxf(M3, e3);
    }
    float S0 = 0.f, S1 = 0.f, S2 = 0.f, S3 = 0.f;
    for (int c = lo; c < hi; c += 64) {
      int j = c + lane;
      int sv = (j < hi) ? csr_src[j] : 0;
      float4 a4 = ((const float4*)asrc)[sv];
      bool valid = (j < hi);
      float e0 = valid ? lrelu(a4.x + ad4.x) : -1e30f;
      float e1 = valid ? lrelu(a4.y + ad4.y) : -1e30f;
      float e2 = valid ? lrelu(a4.z + ad4.z) : -1e30f;
      float e3 = valid ? lrelu(a4.w + ad4.w) : -1e30f;
      float w0 = expf(e0 - M0), w1 = expf(e1 - M1);
      float w2 = expf(e2 - M2), w3 = expf(e3 - M3);
      float s0 = w0, s1 = w1, s2 = w2, s3 = w3;
      BFLY_SUM4(s0, s1, s2, s3)
      S0 += s0; S1 += s1; S2 += s2; S3 += s3;
      sv_lds[wl][lane] = sv;
      *(float4*)&w_lds[wl][lane][0] = make_float4(w0, w1, w2, w3);
      int cnt = (hi - c < 64) ? (hi - c) : 64;
      int jj = 0;
      for (; jj + 4 <= cnt; jj += 4) {
        int i0 = sv_lds[wl][jj + 0], i1 = sv_lds[wl][jj + 1];
        int i2 = sv_lds[wl][jj + 2], i3 = sv_lds[wl][jj + 3];
        float wA = w_lds[wl][jj + 0][head], wB = w_lds[wl][jj + 1][head];
        float wC = w_lds[wl][jj + 2][head], wD = w_lds[wl][jj + 3][head];
        float2 h0 = __half22float2(*(const __half2*)(h + (size_t)i0 * HC + lane * 2));
        float2 h1 = __half22float2(*(const __half2*)(h + (size_t)i1 * HC + lane * 2));
        float2 h2 = __half22float2(*(const __half2*)(h + (size_t)i2 * HC + lane * 2));
        float2 h3 = __half22float2(*(const __half2*)(h + (size_t)i3 * HC + lane * 2));
        ax += wA * h0.x; ay += wA * h0.y;
        ax += wB * h1.x; ay += wB * h1.y;
        ax += wC * h2.x; ay += wC * h2.y;
        ax += wD * h3.x; ay += wD * h3.y;
      }
      for (; jj < cnt; jj++) {
        int i0 = sv_lds[wl][jj];
        float wA = w_lds[wl][jj][head];
        float2 h0 = __half22float2(*(const __half2*)(h + (size_t)i0 * HC + lane * 2));
        ax += wA * h0.x; ay += wA * h0.y;
      }
    }
    S = (head == 0) ? S0 : (head == 1) ? S1 : (head == 2) ? S2 : S3;
  }

  float rden = 1.f / S;
  float2 b = *(const float2*)(bias + lane * 2);
  float vx = fmaxf(ax * rden + b.x, 0.f);
  float vy = fmaxf(ay * rden + b.y, 0.f);
  *(float2*)(out_h + (size_t)node * HC + lane * 2) = make_float2(vx, vy);
  if (do_pool) {
    int g = batch[node];
    unsigned* pp = pooled + g * HC + lane * 2;
    // post-relu values >= 0: bit compare == float compare; init 0 matches the
    // reference's where(isfinite, pooled, 0) empty-graph guard.
    atomicMax(pp + 0, __float_as_uint(vx));
    atomicMax(pp + 1, __float_as_uint(vy));
  }
}

// final head: out[g] = (pooled[g] @ Wlin + blin) @ Wout + bout ; 1 block/graph
__global__ __launch_bounds__(256) void k_mlp(
    const float* __restrict__ pooled, const float* __restrict__ Wlin,
    const float* __restrict__ blin, const float* __restrict__ Wout,
    const float* __restrict__ bout, float* __restrict__ out) {
  __shared__ float p[HC];
  __shared__ float z[LIN];
  int g = blockIdx.x, tid = threadIdx.x;
  if (tid < HC) p[tid] = pooled[g * HC + tid];
  __syncthreads();
  float zv = blin[tid];
  for (int k = 0; k < HC; k++) zv += p[k] * Wlin[k * LIN + tid];
  z[tid] = zv;
  __syncthreads();
  if (tid < OUTC) {
    float o = bout[tid];
    for (int k = 0; k < LIN; k++) o += z[k] * Wout[k * OUTC + tid];
    out[g * OUTC + tid] = o;
  }
}

extern "C" void kernel_launch(void* const* d_in, const int* in_sizes, int n_in,
                              void* d_out, int out_size, void* d_ws, size_t ws_size,
                              hipStream_t stream) {
  const float* x     = (const float*)d_in[0];
  const int*   ei    = (const int*)d_in[1];
  const int*   batch = (const int*)d_in[2];
  const float* Wl[3] = {(const float*)d_in[3], (const float*)d_in[7], (const float*)d_in[11]};
  const float* As[3] = {(const float*)d_in[4], (const float*)d_in[8], (const float*)d_in[12]};
  const float* Ad[3] = {(const float*)d_in[5], (const float*)d_in[9], (const float*)d_in[13]};
  const float* Bi[3] = {(const float*)d_in[6], (const float*)d_in[10], (const float*)d_in[14]};
  const float* Wlin  = (const float*)d_in[15];
  const float* blin  = (const float*)d_in[16];
  const float* Wout  = (const float*)d_in[17];
  const float* bout  = (const float*)d_in[18];
  float* out = (float*)d_out;

  // workspace layout (float offsets); h is fp16 now (N*128 halves = 3.2M floats)
  float* ws = (float*)d_ws;
  __half*   h       = (__half*)ws;                 // N*128 halves
  float*    nodeB   = ws + 6400000;                // N*128 fp32
  float*    asrc    = ws + 12800000;               // N*4
  float*    adst    = ws + 13000000;               // N*4
  int*      deg     = (int*)(ws + 13200000);       // N
  int*      cnt     = (int*)(ws + 13250000);       // N (adjacent to deg)
  int*      row_off = (int*)(ws + 13300000);       // N+1
  int*      csr_src = (int*)(ws + 13350008);       // E_TOT
  unsigned* pooled  = (unsigned*)(ws + 14200008);  // 64*128

  const int* srcp = ei;
  const int* dstp = ei + E_EDGES;

  hipMemsetAsync(deg, 0, 2 * N_NODES * sizeof(int), stream);

  // CSR by dst — built once, reused by all 3 layers
  k_hist<<<(E_TOT + 255) / 256, 256, 0, stream>>>(dstp, deg);
  k_scan<<<1, 1024, 0, stream>>>(deg, row_off, pooled);
  k_scatter<<<(E_TOT + 255) / 256, 256, 0, stream>>>(srcp, dstp, row_off, cnt, csr_src);

  const float* lin_in = x;
  for (int L = 0; L < 3; L++) {
    k_gemm_alpha<<<(N_NODES + 127) / 128, 256, 0, stream>>>(
        lin_in, Wl[L], As[L], Ad[L], h, asrc, adst);
    k_aggr<<<(N_NODES * 64 + 255) / 256, 256, 0, stream>>>(
        row_off, csr_src, asrc, adst, h, Bi[L], batch,
        nodeB, pooled, (L == 2) ? 1 : 0);
    lin_in = nodeB;
  }
  k_mlp<<<NG, 256, 0, stream>>>((const float*)pooled, Wlin, blin, Wout, bout, out);
}